// Round 7
// baseline (210.742 us; speedup 1.0000x reference)
//
#include <hip/hip_runtime.h>

// out[b,i,h,w] = w1 * (w-s1 >= 0 ? x[b,h,w-s1] : 0) + w2 * (w+s2 < 512 ? x[b,h,w+s2] : 0)
// s1 = (i+1)>>1, s2 = (i>>1)+1.  B=2, I=H=W=512.
//
// Round 7: store-sequential mapping. Block = (b, i, h-half) -> s1,s2 are
// BLOCK-UNIFORM scalars and the block writes 512 KB forward-sequentially
// (fill-like), vs round 6's 4 KB chunks at 1 MiB stride. Reads come from the
// L1/L2-resident 2 MiB input via aligned f32x4 loads + static shufflevector
// (template<A1,A2> dispatch over the uniform sub-word shifts). Boundary masks
// fold into loop-invariant premasked weight vectors (no per-iter cndmask).

typedef float f32x4 __attribute__((ext_vector_type(4)));

template <int A1, int A2>
__device__ __forceinline__ void run_block(const float* __restrict__ xb,
                                          f32x4* __restrict__ ob,
                                          int s1, int s2, int h0,
                                          float w1, float w2)
{
    const int t  = threadIdx.x;
    const int w4 = t & 127;            // fixed per thread (256 ≡ 0 mod 128)
    const int w0 = w4 << 2;
    const int q1 = s1 >> 2, q2 = s2 >> 2;

    // loop-invariant element offsets within a row (clamped; masks zero the rest)
    const int Lhi_off = max(w0 - (q1 << 2), 0);
    const int Llo_off = max(w0 - (q1 << 2) - 4, 0);
    const int Rlo_off = min(w0 + (q2 << 2), 508);
    const int Rhi_off = min(w0 + (q2 << 2) + 4, 508);

    // premasked weights: W1[k] = (w0+k >= s1) ? w1 : 0 ; W2[k] = (w0+k+s2 < 512) ? w2 : 0
    f32x4 W1, W2;
    W1.x = (w0 + 0 >= s1) ? w1 : 0.f;  W2.x = (w0 + 0 + s2 < 512) ? w2 : 0.f;
    W1.y = (w0 + 1 >= s1) ? w1 : 0.f;  W2.y = (w0 + 1 + s2 < 512) ? w2 : 0.f;
    W1.z = (w0 + 2 >= s1) ? w1 : 0.f;  W2.z = (w0 + 2 + s2 < 512) ? w2 : 0.f;
    W1.w = (w0 + 3 >= s1) ? w1 : 0.f;  W2.w = (w0 + 3 + s2 < 512) ? w2 : 0.f;

    const float* xr = xb + ((h0 + (t >> 7)) << 9);   // row h = h0 + 2*iter + (t>>7)
    f32x4* op = ob + t;                              // chunk c = iter*256 + t

    for (int iter = 0; iter < 128; ++iter) {
        f32x4 A, B;
        {
            const f32x4 Lhi = *(const f32x4*)(xr + Lhi_off);
            if constexpr (A1 == 0) {
                A = Lhi;
            } else {
                const f32x4 Llo = *(const f32x4*)(xr + Llo_off);
                A = __builtin_shufflevector(Llo, Lhi, 4 - A1, 5 - A1, 6 - A1, 7 - A1);
            }
        }
        {
            const f32x4 Rlo = *(const f32x4*)(xr + Rlo_off);
            if constexpr (A2 == 0) {
                B = Rlo;
            } else {
                const f32x4 Rhi = *(const f32x4*)(xr + Rhi_off);
                B = __builtin_shufflevector(Rlo, Rhi, A2, A2 + 1, A2 + 2, A2 + 3);
            }
        }
        f32x4 v;
        v.x = W1.x * A.x + W2.x * B.x;
        v.y = W1.y * A.y + W2.y * B.y;
        v.z = W1.z * A.z + W2.z * B.z;
        v.w = W1.w * A.w + W2.w * B.w;
        *op = v;                    // block-sequential: 4 KB/iter, ascending
        op += 256;
        xr += 1024;                 // +2 rows
    }
}

__global__ __launch_bounds__(256) void StereoConv_kernel(
    const float* __restrict__ x,     // (2, 512, 512) == x[:,0]
    const float* __restrict__ w1p,
    const float* __restrict__ w2p,
    f32x4* __restrict__ out4)        // (2, 512, 512, 512) as f32x4[.., 128]
{
    const int bid = blockIdx.x;
    const int b   = bid >> 10;
    const int i   = (bid >> 1) & 511;
    const int h0  = (bid & 1) << 8;          // 0 or 256
    const int s1  = (i + 1) >> 1;
    const int s2  = (i >> 1) + 1;
    const int a1  = s1 & 3, a2 = s2 & 3;

    const float* xb = x + ((size_t)b << 18);                     // x[b,:,:]
    f32x4* ob = out4 + (((((size_t)(b << 9)) | i) << 9 | h0) << 7);
    const float w1 = w1p[0], w2 = w2p[0];

#define RB_CASE(A1v, A2v) \
    case ((A1v << 2) | A2v): run_block<A1v, A2v>(xb, ob, s1, s2, h0, w1, w2); break;

    switch ((a1 << 2) | a2) {
        RB_CASE(0, 0) RB_CASE(0, 1) RB_CASE(0, 2) RB_CASE(0, 3)
        RB_CASE(1, 0) RB_CASE(1, 1) RB_CASE(1, 2) RB_CASE(1, 3)
        RB_CASE(2, 0) RB_CASE(2, 1) RB_CASE(2, 2) RB_CASE(2, 3)
        RB_CASE(3, 0) RB_CASE(3, 1) RB_CASE(3, 2) RB_CASE(3, 3)
    }
#undef RB_CASE
}

extern "C" void kernel_launch(void* const* d_in, const int* in_sizes, int n_in,
                              void* d_out, int out_size, void* d_ws, size_t ws_size,
                              hipStream_t stream) {
    const float* x  = (const float*)d_in[0];
    const float* w1 = (const float*)d_in[1];
    const float* w2 = (const float*)d_in[2];
    f32x4* out4 = (f32x4*)d_out;

    // 2048 blocks = 2 b * 512 i * 2 h-halves; each writes 512 KB sequentially
    StereoConv_kernel<<<2048, 256, 0, stream>>>(x, w1, w2, out4);
}

// Round 8
// 198.575 us; speedup vs baseline: 1.0613x; 1.0613x over previous
//
#include <hip/hip_runtime.h>

// out[b,i,h,w] = w1 * (w-s1 >= 0 ? x[b,h,w-s1] : 0) + w2 * (w+s2 < 512 ? x[b,h,w+s2] : 0)
// s1 = (i+1)>>1, s2 = (i>>1)+1.  B=2, I=H=W=512.
//
// Round 8 = round 6 (best, 189 us) + XCD-chunked blockIdx swizzle.
// Round-6 bid bits = [half:2][b:1][hpair:8]; swizzle (bid&7)*256 + bid>>3 gives
// each XCD one fixed (half,b) -> a contiguous 128 MiB output slab; at any
// instant an XCD's 256 resident blocks write one contiguous 1 MiB i-plane.
// Mechanism: per-L2 writeback spatial locality (currently 4 KB chunks at
// 32 KB stride per L2). Bijective: 2048 % 8 == 0.
// Everything else identical to round 6: LDS-staged 2 x-rows, i-blocked by 8,
// 4 aligned f32x4 LDS window reads -> 8 f32x4 global stores per thread per t.

typedef float f32x4 __attribute__((ext_vector_type(4)));

__global__ __launch_bounds__(256) void StereoConv_kernel(
    const float* __restrict__ x,     // (2, 512, 512) == x[:,0]
    const float* __restrict__ w1p,   // scalar
    const float* __restrict__ w2p,   // scalar
    f32x4* __restrict__ out4)        // (2, 512, 512, 512) as f32x4[.., 128]
{
    __shared__ __align__(16) float lds[2][512];   // this block's 2 x-rows

    // XCD-chunked swizzle: hardware round-robins blockIdx across 8 XCDs;
    // remap so XCD k owns logical bids [k*256, (k+1)*256) = contiguous slab.
    const int bid = ((blockIdx.x & 7) << 8) | (blockIdx.x >> 3);

    const int tid  = bid * 256 + threadIdx.x;         // 0 .. 2^19-1
    const int w4   = tid & 127;
    const int h    = (tid >> 7) & 511;                // = 2*bid + (threadIdx>>7), mod 512
    const int b    = (tid >> 16) & 1;                 // block-uniform
    const int half = tid >> 17;                       // 0..3, block-uniform

    // ---- stage: 2 rows x 512 floats = 256 f32x4, one per thread ----
    {
        const int r = threadIdx.x >> 7;               // 0..1
        const int c = threadIdx.x & 127;              // f32x4 column
        const int hbase = (bid * 2) & 511;            // block's first h (even)
        const float* srcrow = x + (((b << 9) + hbase + r) << 9);
        *(f32x4*)&lds[r][c << 2] = *(const f32x4*)(srcrow + (c << 2));
    }
    __syncthreads();

    const float w1 = w1p[0];
    const float w2 = w2p[0];
    const int w0 = w4 << 2;
    const float* __restrict__ row = &lds[threadIdx.x >> 7][0];   // this thread's x-row

    for (int t = 0; t < 16; ++t) {
        const int it = (half << 4) | t;    // 0..63
        const int i0 = it << 3;            // 0,8,...,504
        const int W  = w0 - (it << 2);     // left window base (mod 4 == 0)
        const int V  = w0 + (it << 2);     // right window base (mod 4 == 0)

        f32x4 l0 = *(const f32x4*)(row + max(W - 4, 0));   // xs[W-4..W-1], valid iff W >= 4
        f32x4 l1 = *(const f32x4*)(row + max(W, 0));       // xs[W  ..W+3], valid iff W >= 0
        f32x4 r0 = *(const f32x4*)(row + min(V, 508));     // xs[V  ..V+3], valid iff V < 512
        f32x4 r1 = *(const f32x4*)(row + min(V + 4, 508)); // xs[V+4..V+7], valid iff V+4 < 512
        const f32x4 z = {0.f, 0.f, 0.f, 0.f};
        if (W < 4)    l0 = z;
        if (W < 0)    l1 = z;
        if (V >= 512) r0 = z;
        if (V >= 508) r1 = z;

        const float L[8] = {l0.x, l0.y, l0.z, l0.w, l1.x, l1.y, l1.z, l1.w};
        const float R[8] = {r0.x, r0.y, r0.z, r0.w, r1.x, r1.y, r1.z, r1.w};

        // out4 flat index: ((b*512 + i)*512 + h)*128 + w4, i = i0 + d
        const size_t obase = ((((size_t)(b << 9) + i0) << 9 | h) << 7) | w4;

#pragma unroll
        for (int d = 0; d < 8; ++d) {
            const int la = 4 - ((d + 1) >> 1);   // 4,3,3,2,2,1,1,0
            const int ra = (d >> 1) + 1;         // 1,1,2,2,3,3,4,4
            f32x4 v;
            v.x = w1 * L[la + 0] + w2 * R[ra + 0];
            v.y = w1 * L[la + 1] + w2 * R[ra + 1];
            v.z = w1 * L[la + 2] + w2 * R[ra + 2];
            v.w = w1 * L[la + 3] + w2 * R[ra + 3];
            out4[obase + (size_t)d * (512 * 128)] = v;
        }
    }
}

extern "C" void kernel_launch(void* const* d_in, const int* in_sizes, int n_in,
                              void* d_out, int out_size, void* d_ws, size_t ws_size,
                              hipStream_t stream) {
    const float* x  = (const float*)d_in[0];
    const float* w1 = (const float*)d_in[1];
    const float* w2 = (const float*)d_in[2];
    f32x4* out4 = (f32x4*)d_out;

    // 2048 blocks * 256 threads * 16 iters * 8 f32x4-stores = 2^30 B = full output
    StereoConv_kernel<<<2048, 256, 0, stream>>>(x, w1, w2, out4);
}

// Round 9
// 189.165 us; speedup vs baseline: 1.1141x; 1.0497x over previous
//
#include <hip/hip_runtime.h>

// out[b,i,h,w] = w1 * (w-s1 >= 0 ? x[b,h,w-s1] : 0) + w2 * (w+s2 < 512 ? x[b,h,w+s2] : 0)
// s1 = (i+1)>>1, s2 = (i>>1)+1.  B=2, I=H=W=512.
//
// FINAL (= round 6, best at 189.2 us, 5.68 TB/s effective store BW = 86% of
// fillBufferAligned's 6.6 TB/s on this same buffer).
// A/B ledger: grid-stride (neutral), nontemporal stores (neutral), LDS read
// staging (+5%), store-sequential mapping (-11%), XCD-chunked swizzle (-5%).
//
// Structure: block owns 2 x-rows (4 KB) staged to LDS once; i-blocked by 8:
//   idx1 window xs[W-4..W+3], idx2 window xs[V..V+7], W = w0-4it, V = w0+4it,
//   both 16B-aligned -> 4 ds_read_b128 + 8 global f32x4 stores per thread per t.
// Whole-chunk boundary masking (W,V = 0 mod 4 -> chunks never straddle 0/512).

typedef float f32x4 __attribute__((ext_vector_type(4)));

__global__ __launch_bounds__(256) void StereoConv_kernel(
    const float* __restrict__ x,     // (2, 512, 512) == x[:,0]
    const float* __restrict__ w1p,   // scalar
    const float* __restrict__ w2p,   // scalar
    f32x4* __restrict__ out4)        // (2, 512, 512, 512) as f32x4[.., 128]
{
    __shared__ __align__(16) float lds[2][512];   // this block's 2 x-rows

    const int tid  = blockIdx.x * 256 + threadIdx.x;  // 0 .. 2^19-1
    const int w4   = tid & 127;
    const int h    = (tid >> 7) & 511;                // = 2*blockIdx + (threadIdx>>7), mod 512
    const int b    = (tid >> 16) & 1;                 // block-uniform
    const int half = tid >> 17;                       // 0..3, block-uniform

    // ---- stage: 2 rows x 512 floats = 256 f32x4, one per thread ----
    {
        const int r = threadIdx.x >> 7;               // 0..1
        const int c = threadIdx.x & 127;              // f32x4 column
        const int hbase = (blockIdx.x * 2) & 511;     // block's first h (even)
        const float* srcrow = x + (((b << 9) + hbase + r) << 9);
        *(f32x4*)&lds[r][c << 2] = *(const f32x4*)(srcrow + (c << 2));
    }
    __syncthreads();

    const float w1 = w1p[0];
    const float w2 = w2p[0];
    const int w0 = w4 << 2;
    const float* __restrict__ row = &lds[threadIdx.x >> 7][0];   // this thread's x-row

    for (int t = 0; t < 16; ++t) {
        const int it = (half << 4) | t;    // 0..63
        const int i0 = it << 3;            // 0,8,...,504
        const int W  = w0 - (it << 2);     // left window base (mod 4 == 0)
        const int V  = w0 + (it << 2);     // right window base (mod 4 == 0)

        f32x4 l0 = *(const f32x4*)(row + max(W - 4, 0));   // xs[W-4..W-1], valid iff W >= 4
        f32x4 l1 = *(const f32x4*)(row + max(W, 0));       // xs[W  ..W+3], valid iff W >= 0
        f32x4 r0 = *(const f32x4*)(row + min(V, 508));     // xs[V  ..V+3], valid iff V < 512
        f32x4 r1 = *(const f32x4*)(row + min(V + 4, 508)); // xs[V+4..V+7], valid iff V+4 < 512
        const f32x4 z = {0.f, 0.f, 0.f, 0.f};
        if (W < 4)    l0 = z;
        if (W < 0)    l1 = z;
        if (V >= 512) r0 = z;
        if (V >= 508) r1 = z;

        const float L[8] = {l0.x, l0.y, l0.z, l0.w, l1.x, l1.y, l1.z, l1.w};
        const float R[8] = {r0.x, r0.y, r0.z, r0.w, r1.x, r1.y, r1.z, r1.w};

        // out4 flat index: ((b*512 + i)*512 + h)*128 + w4, i = i0 + d
        const size_t obase = ((((size_t)(b << 9) + i0) << 9 | h) << 7) | w4;

#pragma unroll
        for (int d = 0; d < 8; ++d) {
            const int la = 4 - ((d + 1) >> 1);   // 4,3,3,2,2,1,1,0
            const int ra = (d >> 1) + 1;         // 1,1,2,2,3,3,4,4
            f32x4 v;
            v.x = w1 * L[la + 0] + w2 * R[ra + 0];
            v.y = w1 * L[la + 1] + w2 * R[ra + 1];
            v.z = w1 * L[la + 2] + w2 * R[ra + 2];
            v.w = w1 * L[la + 3] + w2 * R[ra + 3];
            out4[obase + (size_t)d * (512 * 128)] = v;
        }
    }
}

extern "C" void kernel_launch(void* const* d_in, const int* in_sizes, int n_in,
                              void* d_out, int out_size, void* d_ws, size_t ws_size,
                              hipStream_t stream) {
    const float* x  = (const float*)d_in[0];
    const float* w1 = (const float*)d_in[1];
    const float* w2 = (const float*)d_in[2];
    f32x4* out4 = (f32x4*)d_out;

    // 2048 blocks * 256 threads * 16 iters * 8 f32x4-stores = 2^30 B = full output
    StereoConv_kernel<<<2048, 256, 0, stream>>>(x, w1, w2, out4);
}